// Round 7
// baseline (116.995 us; speedup 1.0000x reference)
//
#include <hip/hip_runtime.h>
#include <hip/hip_bf16.h>

// flex_conv via MFMA + BARRIER-FREE per-wave async LDS staging.
// t[k=ic*4+d][pixel]: t_d = ctr_d*Xs - PX_d (d<3), t_3 = Xs
// out[o][pixel] = Kmat[o][k] . t[k][pixel]  -> 16x16x32 bf16 MFMA
// (A[m=p][k=c*8+..], B[k][n=p], D row=c*4+r col=p — validated R2-R6).
//
// Each WAVE owns a 16-col x RB=4-row tile and stages its own
// 19 planes x 6 rows x 20 cols window into its private LDS quarter via
// global_load_lds (9 coalesced 1-KB wave-instrs), then waits with a
// wave-local s_waitcnt vmcnt(0). NO __syncthreads anywhere -> no block
// convoys; 16 independent waves/CU hide the one latency exposure.
// Bank math: x c-group stride = 2 planes = 240 floats = 16 mod 32 banks
// -> 2-way conflicts only (free per m136).

#define HH 64
#define WW 512
#define HP 62
#define WP 510
#define IC 16
#define OC 32
#define BS 16
#define RB 4              // output rows per wave-tile
#define TRW 6             // staged input rows
#define LCW 20            // staged cols per row (16 + 2 halo, padded to 5 chunks)
#define NPL 19            // planes: 16 x + 3 pts
#define WROWS (NPL * TRW)          // 114 (plane,row) pairs
#define WCHUNK (WROWS * 5)         // 570 16-B chunks per wave
#define WFLOATS (WCHUNK * 4)       // 2280 floats = 9120 B per wave

typedef __attribute__((ext_vector_type(8))) short short8;
typedef __attribute__((ext_vector_type(4))) float f32x4;

static __device__ __forceinline__ short f2bf(float f) {
    union { __hip_bfloat16 h; short s; } u;
    u.h = __float2bfloat16(f);
    return u.s;
}

__global__ __launch_bounds__(256) void flex_conv_wave(
    const float* __restrict__ x, const float* __restrict__ kern,
    const float* __restrict__ pts, float* __restrict__ out)
{
    __shared__ float lds[4 * WFLOATS];   // 36480 B -> 4 blocks/CU

    const int tid = threadIdx.x;
    const int lane = tid & 63;
    const int wave = tid >> 6;
    const int strip = blockIdx.x * 4 + wave;   // 0..31
    const int j0 = strip * 16;
    const int i0t = blockIdx.y * RB;           // 0,4,..,60
    const int i0 = (i0t > HP - RB) ? (HP - RB) : i0t;  // tile 15 -> 58 (dup rows benign: identical values)
    const int b = blockIdx.z;

    float* wlds = &lds[wave * WFLOATS];
    const float* xb = x + (size_t)b * IC * HH * WW;
    const float* pb = pts + (size_t)b * 3 * HH * WW;

    // ---- per-wave async staging: 570 16-B chunks, 9 coalesced wave-instrs ----
    #pragma unroll
    for (int r = 0; r < 9; ++r) {
        const int cid = r * 64 + lane;
        if (cid < WCHUNK) {
            const int row = cid / 5;             // 0..113 = plane*TRW + rr
            const int ch = cid - row * 5;        // 0..4
            const int plane = row / TRW;         // 0..18
            const int rr = row - plane * TRW;    // 0..5
            const float* base = (plane < IC)
                ? (xb + (size_t)plane * HH * WW)
                : (pb + (size_t)(plane - IC) * HH * WW);
            int gcol = j0 + ch * 4;
            if (gcol > WW - 4) gcol = WW - 4;    // strip 31 clamp; active lanes never read it
            const float* g = base + (size_t)(i0 + rr) * WW + gcol;
            __builtin_amdgcn_global_load_lds(
                (const __attribute__((address_space(1))) void*)g,
                (__attribute__((address_space(3))) void*)(wlds + (size_t)cid * 4),
                16, 0, 0);
        }
    }

    // ---- A fragments (independent global loads; overlap staging) ----
    const int p = lane & 15;
    const int c = lane >> 4;

    short8 a0lo, a0hi, a1lo, a1hi;
    {
        const float4* k0v = (const float4*)(kern + (size_t)p * 64 + c * 8);
        const float4* k1v = (const float4*)(kern + (size_t)(16 + p) * 64 + c * 8);
        float4 v0a = k0v[0], v0b = k0v[1], v0c = k0v[8], v0d = k0v[9];
        float4 v1a = k1v[0], v1b = k1v[1], v1c = k1v[8], v1d = k1v[9];
        a0lo[0]=f2bf(v0a.x); a0lo[1]=f2bf(v0a.y); a0lo[2]=f2bf(v0a.z); a0lo[3]=f2bf(v0a.w);
        a0lo[4]=f2bf(v0b.x); a0lo[5]=f2bf(v0b.y); a0lo[6]=f2bf(v0b.z); a0lo[7]=f2bf(v0b.w);
        a0hi[0]=f2bf(v0c.x); a0hi[1]=f2bf(v0c.y); a0hi[2]=f2bf(v0c.z); a0hi[3]=f2bf(v0c.w);
        a0hi[4]=f2bf(v0d.x); a0hi[5]=f2bf(v0d.y); a0hi[6]=f2bf(v0d.z); a0hi[7]=f2bf(v0d.w);
        a1lo[0]=f2bf(v1a.x); a1lo[1]=f2bf(v1a.y); a1lo[2]=f2bf(v1a.z); a1lo[3]=f2bf(v1a.w);
        a1lo[4]=f2bf(v1b.x); a1lo[5]=f2bf(v1b.y); a1lo[6]=f2bf(v1b.z); a1lo[7]=f2bf(v1b.w);
        a1hi[0]=f2bf(v1c.x); a1hi[1]=f2bf(v1c.y); a1hi[2]=f2bf(v1c.z); a1hi[3]=f2bf(v1c.w);
        a1hi[4]=f2bf(v1d.x); a1hi[5]=f2bf(v1d.y); a1hi[6]=f2bf(v1d.z); a1hi[7]=f2bf(v1d.w);
    }

    // ---- wave-local drain of staging loads (no barrier!) ----
    // imm: vmcnt=0, expcnt=7 (ignore), lgkmcnt=15 (ignore) -> 0xF70
    __builtin_amdgcn_s_waitcnt(0x0F70);

    // ---- window partials from this wave's LDS ----
    float xs[4][RB], px0[4][RB], px1[4][RB], px2[4][RB];
    #pragma unroll
    for (int t = 0; t < 4; ++t)
        #pragma unroll
        for (int q = 0; q < RB; ++q) { xs[t][q]=0.f; px0[t][q]=0.f; px1[t][q]=0.f; px2[t][q]=0.f; }
    float c0v[RB], c1v[RB], c2v[RB];

    #pragma unroll
    for (int rr = 0; rr < TRW; ++rr) {
        const float* lp0 = &wlds[(IC * TRW + rr) * LCW + p];
        const float* lp1 = &wlds[((IC + 1) * TRW + rr) * LCW + p];
        const float* lp2 = &wlds[((IC + 2) * TRW + rr) * LCW + p];
        const float pa0 = lp0[0], pm0 = lp0[1], pz0 = lp0[2];
        const float pa1 = lp1[0], pm1 = lp1[1], pz1 = lp1[2];
        const float pa2 = lp2[0], pm2 = lp2[1], pz2 = lp2[2];
        if (rr >= 1 && rr <= RB) { c0v[rr-1] = pm0; c1v[rr-1] = pm1; c2v[rr-1] = pm2; }
        #pragma unroll
        for (int t = 0; t < 4; ++t) {
            const int ic = (t >> 1) * 8 + 2 * c + (t & 1);
            const float* lx = &wlds[(ic * TRW + rr) * LCW + p];
            const float x0 = lx[0], x1 = lx[1], x2 = lx[2];
            const float rsx = x0 + x1 + x2;
            float r0 = pa0 * x0; r0 = fmaf(pm0, x1, r0); r0 = fmaf(pz0, x2, r0);
            float r1 = pa1 * x0; r1 = fmaf(pm1, x1, r1); r1 = fmaf(pz1, x2, r1);
            float r2 = pa2 * x0; r2 = fmaf(pm2, x1, r2); r2 = fmaf(pz2, x2, r2);
            #pragma unroll
            for (int q = 0; q < RB; ++q) {
                if (rr >= q && rr <= q + 2) {
                    xs[t][q] += rsx; px0[t][q] += r0; px1[t][q] += r1; px2[t][q] += r2;
                }
            }
        }
    }

    // ---- per output row: B fragments -> MFMA -> store ----
    const int j = j0 + p;
    #pragma unroll
    for (int q = 0; q < RB; ++q) {
        short8 blo, bhi;
        #pragma unroll
        for (int t = 0; t < 4; ++t) {
            const short e0 = f2bf(fmaf(c0v[q], xs[t][q], -px0[t][q]));
            const short e1 = f2bf(fmaf(c1v[q], xs[t][q], -px1[t][q]));
            const short e2 = f2bf(fmaf(c2v[q], xs[t][q], -px2[t][q]));
            const short e3 = f2bf(xs[t][q]);
            const int sl = (t & 1) * 4;
            if (t < 2) { blo[sl+0]=e0; blo[sl+1]=e1; blo[sl+2]=e2; blo[sl+3]=e3; }
            else       { bhi[sl+0]=e0; bhi[sl+1]=e1; bhi[sl+2]=e2; bhi[sl+3]=e3; }
        }
        f32x4 acc0 = {0.f,0.f,0.f,0.f}, acc1 = {0.f,0.f,0.f,0.f};
        acc0 = __builtin_amdgcn_mfma_f32_16x16x32_bf16(a0lo, blo, acc0, 0, 0, 0);
        acc0 = __builtin_amdgcn_mfma_f32_16x16x32_bf16(a0hi, bhi, acc0, 0, 0, 0);
        acc1 = __builtin_amdgcn_mfma_f32_16x16x32_bf16(a1lo, blo, acc1, 0, 0, 0);
        acc1 = __builtin_amdgcn_mfma_f32_16x16x32_bf16(a1hi, bhi, acc1, 0, 0, 0);
        if (j < WP) {
            float* ob = out + (size_t)b * OC * HP * WP + (size_t)(i0 + q) * WP + j;
            #pragma unroll
            for (int r = 0; r < 4; ++r) {
                const int o = c * 4 + r;
                ob[(size_t)o * HP * WP]        = acc0[r];
                ob[(size_t)(o + 16) * HP * WP] = acc1[r];
            }
        }
    }
}

extern "C" void kernel_launch(void* const* d_in, const int* in_sizes, int n_in,
                              void* d_out, int out_size, void* d_ws, size_t ws_size,
                              hipStream_t stream)
{
    const float* x    = (const float*)d_in[0];
    const float* kern = (const float*)d_in[1];
    const float* pts  = (const float*)d_in[2];
    float* out = (float*)d_out;

    dim3 block(256, 1, 1);
    // x: 8 col-groups (4 strips/block), y: 16 row-tiles of RB=4 (last clamps), z: batch
    dim3 grid(8, 16, BS);   // 2048 blocks, 8192 independent waves
    flex_conv_wave<<<grid, block, 0, stream>>>(x, kern, pts, out);
}